// Round 4
// baseline (358.149 us; speedup 1.0000x reference)
//
#include <hip/hip_runtime.h>
#include <math.h>

#define NSAMP 256

// Round-3 fix: the feats[] producing loop was only PARTIALLY unrolled
// (#pragma unroll 4), leaving feats[c] runtime-indexed -> compiler put
// feats[32] in scratch. 524288 threads x 128B = 67MB scratch writes,
// matching the observed 80MB WRITE_SIZE. Full unroll -> all indices
// compile-time-constant -> feats lives in VGPRs.
__global__ __launch_bounds__(256, 4) void nerf_fused(
    const float* __restrict__ rays_o, const float* __restrict__ rays_d,
    const float* __restrict__ G1, const float* __restrict__ Fg,
    const float* __restrict__ Wd1, const float* __restrict__ bd1,
    const float* __restrict__ Wd2, const float* __restrict__ bd2,
    const float* __restrict__ Wc1, const float* __restrict__ bc1,
    const float* __restrict__ Wc2, const float* __restrict__ bc2,
    float* __restrict__ out)
{
    const float RADIUS = 1.3f;
    const float STEP = 0.0176f;

    const int b    = blockIdx.x;
    const int tid  = threadIdx.x;
    const int lane = tid & 63;
    const int wv   = tid >> 6;

    __shared__ float s_wtot[4];
    __shared__ float s_red[4][4];

    // ---- ray setup ----
    const float ox = rays_o[b*3+0], oy = rays_o[b*3+1], oz = rays_o[b*3+2];
    const float rdx = rays_d[b*3+0], rdy = rays_d[b*3+1], rdz = rays_d[b*3+2];
    const float rn  = sqrtf(rdx*rdx + rdy*rdy + rdz*rdz);
    const float dxn = rdx/rn, dyn = rdy/rn, dzn = rdz/rn;

    // ---- cube intersection ----
    float sd, inv, t1, t2, tmin, tmax;
    sd = (fabsf(dxn) < 1e-9f) ? 1e-9f : dxn; inv = 1.0f/sd;
    t1 = (-RADIUS - ox)*inv; t2 = (RADIUS - ox)*inv;
    tmin = fminf(t1,t2); tmax = fmaxf(t1,t2);
    sd = (fabsf(dyn) < 1e-9f) ? 1e-9f : dyn; inv = 1.0f/sd;
    t1 = (-RADIUS - oy)*inv; t2 = (RADIUS - oy)*inv;
    tmin = fmaxf(tmin, fminf(t1,t2)); tmax = fminf(tmax, fmaxf(t1,t2));
    sd = (fabsf(dzn) < 1e-9f) ? 1e-9f : dzn; inv = 1.0f/sd;
    t1 = (-RADIUS - oz)*inv; t2 = (RADIUS - oz)*inv;
    tmin = fmaxf(tmin, fminf(t1,t2)); tmax = fminf(tmax, fmaxf(t1,t2));

    const float tnear = fmaxf(tmin, 0.0f);
    const bool  hit   = tmax > tnear;
    const float t     = tnear + STEP * (float)tid;
    const bool  mask  = (t < tmax) && hit;

    // ---- sample position, normalized to [-1,1] ----
    const float invR = 1.0f / RADIUS;
    const float px = (ox + t*dxn) * invR;
    const float py = (oy + t*dyn) * invR;
    const float pz = (oz + t*dzn) * invR;

    // ---- trilinear G1 (C=3, 128^3) ----
    float cox = fminf(fmaxf((px+1.0f)*0.5f*127.0f, 0.0f), 127.0f);
    float coy = fminf(fmaxf((py+1.0f)*0.5f*127.0f, 0.0f), 127.0f);
    float coz = fminf(fmaxf((pz+1.0f)*0.5f*127.0f, 0.0f), 127.0f);
    int x0 = (int)floorf(cox); float fx = cox - (float)x0; int x1 = min(x0+1, 127);
    int y0 = (int)floorf(coy); float fy = coy - (float)y0; int y1 = min(y0+1, 127);
    int z0 = (int)floorf(coz); float fz = coz - (float)z0; int z1 = min(z0+1, 127);

    {
        const float wx0 = 1.0f-fx, wx1 = fx;
        const float wy0 = 1.0f-fy, wy1 = fy;
        const float wz0 = 1.0f-fz, wz1 = fz;
        const float w000 = wx0*wy0*wz0, w100 = wx1*wy0*wz0;
        const float w010 = wx0*wy1*wz0, w110 = wx1*wy1*wz0;
        const float w001 = wx0*wy0*wz1, w101 = wx1*wy0*wz1;
        const float w011 = wx0*wy1*wz1, w111 = wx1*wy1*wz1;
        const int i000 = (z0*128 + y0)*128 + x0;
        const int dxo = x1 - x0;
        const int dyo = (y1 - y0)*128;
        const int dzo = (z1 - z0)*16384;
        const int i100 = i000 + dxo,       i010 = i000 + dyo;
        const int i110 = i000 + dyo + dxo, i001 = i000 + dzo;
        const int i101 = i000 + dzo + dxo, i011 = i000 + dzo + dyo;
        const int i111 = i000 + dzo + dyo + dxo;

        float g[3];
        #pragma unroll
        for (int c = 0; c < 3; ++c) {
            const float* gp = G1 + (size_t)c * 2097152;
            g[c] = w000*gp[i000] + w100*gp[i100] + w010*gp[i010] + w110*gp[i110]
                 + w001*gp[i001] + w101*gp[i101] + w011*gp[i011] + w111*gp[i111];
        }

        // ---- F coords from g ----
        cox = fminf(fmaxf((g[0]+1.0f)*0.5f*31.0f, 0.0f), 31.0f);
        coy = fminf(fmaxf((g[1]+1.0f)*0.5f*31.0f, 0.0f), 31.0f);
        coz = fminf(fmaxf((g[2]+1.0f)*0.5f*31.0f, 0.0f), 31.0f);
        x0 = (int)floorf(cox); fx = cox - (float)x0; x1 = min(x0+1, 31);
        y0 = (int)floorf(coy); fy = coy - (float)y0; y1 = min(y0+1, 31);
        z0 = (int)floorf(coz); fz = coz - (float)z0; z1 = min(z0+1, 31);
    }

    // ---- trilinear F (C=32, 32^3): FULL unroll, feats stays in VGPRs ----
    float feats[32];
    {
        const float wx0 = 1.0f-fx, wx1 = fx;
        const float wy0 = 1.0f-fy, wy1 = fy;
        const float wz0 = 1.0f-fz, wz1 = fz;
        const float w000 = wx0*wy0*wz0, w100 = wx1*wy0*wz0;
        const float w010 = wx0*wy1*wz0, w110 = wx1*wy1*wz0;
        const float w001 = wx0*wy0*wz1, w101 = wx1*wy0*wz1;
        const float w011 = wx0*wy1*wz1, w111 = wx1*wy1*wz1;
        const int j000 = (z0*32 + y0)*32 + x0;
        const int dxo = x1 - x0;
        const int dyo = (y1 - y0)*32;
        const int dzo = (z1 - z0)*1024;
        const int j100 = j000 + dxo,       j010 = j000 + dyo;
        const int j110 = j000 + dyo + dxo, j001 = j000 + dzo;
        const int j101 = j000 + dzo + dxo, j011 = j000 + dzo + dyo;
        const int j111 = j000 + dzo + dyo + dxo;

        #pragma unroll
        for (int c = 0; c < 32; ++c) {
            const float* fp = Fg + (size_t)c * 32768;
            feats[c] = w000*fp[j000] + w100*fp[j100] + w010*fp[j010] + w110*fp[j110]
                     + w001*fp[j001] + w101*fp[j101] + w011*fp[j011] + w111*fp[j111];
        }
    }

    // ---- fused MLPs (density + color share feats reads) ----
    float sigma = bd2[0];
    float cr = 0.0f, cg = 0.0f, cb = 0.0f;
    #pragma unroll
    for (int j0 = 0; j0 < 64; j0 += 8) {
        float ad[8], ac[8];
        #pragma unroll
        for (int jj = 0; jj < 8; ++jj) {
            ad[jj] = bd1[j0+jj];
            ac[jj] = bc1[j0+jj] + dxn*Wc1[32*64 + j0 + jj]
                                + dyn*Wc1[33*64 + j0 + jj]
                                + dzn*Wc1[34*64 + j0 + jj];
        }
        #pragma unroll
        for (int k = 0; k < 32; ++k) {
            const float fv = feats[k];
            #pragma unroll
            for (int jj = 0; jj < 8; ++jj) {
                ad[jj] += fv * Wd1[k*64 + j0 + jj];
                ac[jj] += fv * Wc1[k*64 + j0 + jj];
            }
        }
        #pragma unroll
        for (int jj = 0; jj < 8; ++jj) {
            sigma += fmaxf(ad[jj], 0.0f) * Wd2[j0+jj];
            const float hc = fmaxf(ac[jj], 0.0f);
            cr += hc * Wc2[(j0+jj)*3 + 0];
            cg += hc * Wc2[(j0+jj)*3 + 1];
            cb += hc * Wc2[(j0+jj)*3 + 2];
        }
    }
    cr += bc2[0]; cg += bc2[1]; cb += bc2[2];
    float rr = 1.0f/(1.0f + expf(-cr));
    float rg = 1.0f/(1.0f + expf(-cg));
    float rb = 1.0f/(1.0f + expf(-cb));

    // ---- masking ----
    const float sig_m = mask ? sigma : 0.0f;
    rr = mask ? rr : 0.0f;
    rg = mask ? rg : 0.0f;
    rb = mask ? rb : 0.0f;

    // ---- alpha, exclusive product scan (T_excl), weights ----
    const float alpha = 1.0f - expf(-fmaxf(sig_m, 0.0f) * STEP);
    float p = 1.0f - alpha + 1e-10f;

    float scan = p;
    #pragma unroll
    for (int off = 1; off < 64; off <<= 1) {
        const float n = __shfl_up(scan, off, 64);
        if (lane >= off) scan *= n;
    }
    if (lane == 63) s_wtot[wv] = scan;
    __syncthreads();

    float pre = 1.0f;
    #pragma unroll
    for (int q = 0; q < 4; ++q) if (q < wv) pre *= s_wtot[q];
    float excl = __shfl_up(scan, 1, 64);
    if (lane == 0) excl = 1.0f;
    const float Texcl = pre * excl;

    const float w = alpha * Texcl;
    float sw  = w;
    float swr = w * rr, swg = w * rg, swb = w * rb;

    // ---- block reduction ----
    #pragma unroll
    for (int off = 32; off > 0; off >>= 1) {
        sw  += __shfl_down(sw,  off, 64);
        swr += __shfl_down(swr, off, 64);
        swg += __shfl_down(swg, off, 64);
        swb += __shfl_down(swb, off, 64);
    }
    if (lane == 0) {
        s_red[wv][0] = sw;  s_red[wv][1] = swr;
        s_red[wv][2] = swg; s_red[wv][3] = swb;
    }
    __syncthreads();
    if (tid == 0) {
        float W = 0.0f, R = 0.0f, Gc = 0.0f, Bc = 0.0f;
        #pragma unroll
        for (int q = 0; q < 4; ++q) {
            W  += s_red[q][0]; R  += s_red[q][1];
            Gc += s_red[q][2]; Bc += s_red[q][3];
        }
        const float bg = 1.0f - W;
        out[b*3+0] = R  + bg;
        out[b*3+1] = Gc + bg;
        out[b*3+2] = Bc + bg;
    }
}

extern "C" void kernel_launch(void* const* d_in, const int* in_sizes, int n_in,
                              void* d_out, int out_size, void* d_ws, size_t ws_size,
                              hipStream_t stream) {
    const float* rays_o = (const float*)d_in[0];
    const float* rays_d = (const float*)d_in[1];
    const float* G1     = (const float*)d_in[2];
    const float* Fg     = (const float*)d_in[3];
    const float* Wd1    = (const float*)d_in[4];
    const float* bd1    = (const float*)d_in[5];
    const float* Wd2    = (const float*)d_in[6];
    const float* bd2    = (const float*)d_in[7];
    const float* Wc1    = (const float*)d_in[8];
    const float* bc1    = (const float*)d_in[9];
    const float* Wc2    = (const float*)d_in[10];
    const float* bc2    = (const float*)d_in[11];
    float* out = (float*)d_out;

    const int B = in_sizes[0] / 3;   // 2048 rays
    nerf_fused<<<dim3(B), dim3(NSAMP), 0, stream>>>(
        rays_o, rays_d, G1, Fg, Wd1, bd1, Wd2, bd2, Wc1, bc1, Wc2, bc2, out);
}

// Round 5
// 227.176 us; speedup vs baseline: 1.5765x; 1.5765x over previous
//
#include <hip/hip_runtime.h>
#include <math.h>

#define NSAMP 256

// Pre-pass: transpose F [32 ch][32768 vox] -> Ft [32768 vox][32 ch] so the
// main kernel's per-corner channel gather is 8 contiguous float4 loads.
__global__ __launch_bounds__(256) void transpose_F(
    const float* __restrict__ Fg, float* __restrict__ Ft)
{
    const int j = blockIdx.x * 256 + threadIdx.x;   // voxel id 0..32767
    float4 o[8];
    #pragma unroll
    for (int q = 0; q < 8; ++q) {
        o[q].x = Fg[(size_t)(4*q+0)*32768 + j];
        o[q].y = Fg[(size_t)(4*q+1)*32768 + j];
        o[q].z = Fg[(size_t)(4*q+2)*32768 + j];
        o[q].w = Fg[(size_t)(4*q+3)*32768 + j];
    }
    float4* dst = (float4*)(Ft + (size_t)j * 32);
    #pragma unroll
    for (int q = 0; q < 8; ++q) dst[q] = o[q];
}

// Round-5: the allocator was TARGETING 8 waves/EU (64 VGPR) and spilling
// ~336B/thread to get there (WRITE_SIZE 176MB vs 24KB output).
// amdgpu_waves_per_eu(2,4) caps the occupancy target at 4 waves/EU ->
// 128-VGPR budget, removing the incentive to spill.
template<bool USE_T>
__global__ __launch_bounds__(256) __attribute__((amdgpu_waves_per_eu(2, 4)))
void nerf_fused(
    const float* __restrict__ rays_o, const float* __restrict__ rays_d,
    const float* __restrict__ G1, const float* __restrict__ Fg,
    const float* __restrict__ Wd1, const float* __restrict__ bd1,
    const float* __restrict__ Wd2, const float* __restrict__ bd2,
    const float* __restrict__ Wc1, const float* __restrict__ bc1,
    const float* __restrict__ Wc2, const float* __restrict__ bc2,
    const float* __restrict__ Ft,
    float* __restrict__ out)
{
    const float RADIUS = 1.3f;
    const float STEP = 0.0176f;

    const int b    = blockIdx.x;
    const int tid  = threadIdx.x;
    const int lane = tid & 63;
    const int wv   = tid >> 6;

    __shared__ float s_wtot[4];
    __shared__ float s_red[4][4];

    // ---- ray setup ----
    const float ox = rays_o[b*3+0], oy = rays_o[b*3+1], oz = rays_o[b*3+2];
    const float rdx = rays_d[b*3+0], rdy = rays_d[b*3+1], rdz = rays_d[b*3+2];
    const float rn  = sqrtf(rdx*rdx + rdy*rdy + rdz*rdz);
    const float dxn = rdx/rn, dyn = rdy/rn, dzn = rdz/rn;

    // ---- cube intersection ----
    float sd, inv, t1, t2, tmin, tmax;
    sd = (fabsf(dxn) < 1e-9f) ? 1e-9f : dxn; inv = 1.0f/sd;
    t1 = (-RADIUS - ox)*inv; t2 = (RADIUS - ox)*inv;
    tmin = fminf(t1,t2); tmax = fmaxf(t1,t2);
    sd = (fabsf(dyn) < 1e-9f) ? 1e-9f : dyn; inv = 1.0f/sd;
    t1 = (-RADIUS - oy)*inv; t2 = (RADIUS - oy)*inv;
    tmin = fmaxf(tmin, fminf(t1,t2)); tmax = fminf(tmax, fmaxf(t1,t2));
    sd = (fabsf(dzn) < 1e-9f) ? 1e-9f : dzn; inv = 1.0f/sd;
    t1 = (-RADIUS - oz)*inv; t2 = (RADIUS - oz)*inv;
    tmin = fmaxf(tmin, fminf(t1,t2)); tmax = fminf(tmax, fmaxf(t1,t2));

    const float tnear = fmaxf(tmin, 0.0f);
    const bool  hit   = tmax > tnear;
    const float t     = tnear + STEP * (float)tid;
    const bool  mask  = (t < tmax) && hit;

    // ---- sample position, normalized to [-1,1] ----
    const float invR = 1.0f / RADIUS;
    const float px = (ox + t*dxn) * invR;
    const float py = (oy + t*dyn) * invR;
    const float pz = (oz + t*dzn) * invR;

    // ---- trilinear G1 (C=3, 128^3) ----
    float cox = fminf(fmaxf((px+1.0f)*0.5f*127.0f, 0.0f), 127.0f);
    float coy = fminf(fmaxf((py+1.0f)*0.5f*127.0f, 0.0f), 127.0f);
    float coz = fminf(fmaxf((pz+1.0f)*0.5f*127.0f, 0.0f), 127.0f);
    int x0 = (int)floorf(cox); float fx = cox - (float)x0; int x1 = min(x0+1, 127);
    int y0 = (int)floorf(coy); float fy = coy - (float)y0; int y1 = min(y0+1, 127);
    int z0 = (int)floorf(coz); float fz = coz - (float)z0; int z1 = min(z0+1, 127);

    {
        const float wx0 = 1.0f-fx, wx1 = fx;
        const float wy0 = 1.0f-fy, wy1 = fy;
        const float wz0 = 1.0f-fz, wz1 = fz;
        const float w000 = wx0*wy0*wz0, w100 = wx1*wy0*wz0;
        const float w010 = wx0*wy1*wz0, w110 = wx1*wy1*wz0;
        const float w001 = wx0*wy0*wz1, w101 = wx1*wy0*wz1;
        const float w011 = wx0*wy1*wz1, w111 = wx1*wy1*wz1;
        const int i000 = (z0*128 + y0)*128 + x0;
        const int dxo = x1 - x0;
        const int dyo = (y1 - y0)*128;
        const int dzo = (z1 - z0)*16384;
        const int i100 = i000 + dxo,       i010 = i000 + dyo;
        const int i110 = i000 + dyo + dxo, i001 = i000 + dzo;
        const int i101 = i000 + dzo + dxo, i011 = i000 + dzo + dyo;
        const int i111 = i000 + dzo + dyo + dxo;

        float g[3];
        #pragma unroll
        for (int c = 0; c < 3; ++c) {
            const float* gp = G1 + (size_t)c * 2097152;
            g[c] = w000*gp[i000] + w100*gp[i100] + w010*gp[i010] + w110*gp[i110]
                 + w001*gp[i001] + w101*gp[i101] + w011*gp[i011] + w111*gp[i111];
        }

        // ---- F coords from g ----
        cox = fminf(fmaxf((g[0]+1.0f)*0.5f*31.0f, 0.0f), 31.0f);
        coy = fminf(fmaxf((g[1]+1.0f)*0.5f*31.0f, 0.0f), 31.0f);
        coz = fminf(fmaxf((g[2]+1.0f)*0.5f*31.0f, 0.0f), 31.0f);
        x0 = (int)floorf(cox); fx = cox - (float)x0; x1 = min(x0+1, 31);
        y0 = (int)floorf(coy); fy = cox*0.0f + coy - (float)y0; y1 = min(y0+1, 31);
        z0 = (int)floorf(coz); fz = coz - (float)z0; z1 = min(z0+1, 31);
    }

    // ---- trilinear F (C=32, 32^3), corner-at-a-time accumulation ----
    float feats[32];
    #pragma unroll
    for (int c = 0; c < 32; ++c) feats[c] = 0.0f;
    {
        const float wx0 = 1.0f-fx, wx1 = fx;
        const float wy0 = 1.0f-fy, wy1 = fy;
        const float wz0 = 1.0f-fz, wz1 = fz;
        const int j000 = (z0*32 + y0)*32 + x0;
        const int dxo = x1 - x0;
        const int dyo = (y1 - y0)*32;
        const int dzo = (z1 - z0)*1024;

        const int   jidx[8] = { j000,           j000+dxo,
                                j000+dyo,       j000+dyo+dxo,
                                j000+dzo,       j000+dzo+dxo,
                                j000+dzo+dyo,   j000+dzo+dyo+dxo };
        const float jwt[8]  = { wx0*wy0*wz0, wx1*wy0*wz0,
                                wx0*wy1*wz0, wx1*wy1*wz0,
                                wx0*wy0*wz1, wx1*wy0*wz1,
                                wx0*wy1*wz1, wx1*wy1*wz1 };

        if (USE_T) {
            #pragma unroll
            for (int corner = 0; corner < 8; ++corner) {
                const float4* fp = (const float4*)(Ft + (size_t)jidx[corner] * 32);
                const float w = jwt[corner];
                #pragma unroll
                for (int q = 0; q < 8; ++q) {
                    const float4 v = fp[q];
                    feats[4*q+0] += w * v.x;
                    feats[4*q+1] += w * v.y;
                    feats[4*q+2] += w * v.z;
                    feats[4*q+3] += w * v.w;
                }
            }
        } else {
            #pragma unroll
            for (int corner = 0; corner < 8; ++corner) {
                const float w = jwt[corner];
                const int  j  = jidx[corner];
                #pragma unroll
                for (int c = 0; c < 32; ++c)
                    feats[c] += w * Fg[(size_t)c * 32768 + j];
            }
        }
    }

    // ---- fused MLPs (runtime j0 loop: small code, bounded pressure;
    //      weight accesses are wave-uniform -> scalar loads) ----
    float sigma = bd2[0];
    float cr = 0.0f, cg = 0.0f, cb = 0.0f;
    for (int j0 = 0; j0 < 64; j0 += 8) {
        float ad[8], ac[8];
        #pragma unroll
        for (int jj = 0; jj < 8; ++jj) {
            ad[jj] = bd1[j0+jj];
            ac[jj] = bc1[j0+jj] + dxn*Wc1[32*64 + j0 + jj]
                                + dyn*Wc1[33*64 + j0 + jj]
                                + dzn*Wc1[34*64 + j0 + jj];
        }
        #pragma unroll
        for (int k = 0; k < 32; ++k) {
            const float fv = feats[k];
            #pragma unroll
            for (int jj = 0; jj < 8; ++jj) {
                ad[jj] += fv * Wd1[k*64 + j0 + jj];
                ac[jj] += fv * Wc1[k*64 + j0 + jj];
            }
        }
        #pragma unroll
        for (int jj = 0; jj < 8; ++jj) {
            sigma += fmaxf(ad[jj], 0.0f) * Wd2[j0+jj];
            const float hc = fmaxf(ac[jj], 0.0f);
            cr += hc * Wc2[(j0+jj)*3 + 0];
            cg += hc * Wc2[(j0+jj)*3 + 1];
            cb += hc * Wc2[(j0+jj)*3 + 2];
        }
    }
    cr += bc2[0]; cg += bc2[1]; cb += bc2[2];
    float rr = 1.0f/(1.0f + expf(-cr));
    float rg = 1.0f/(1.0f + expf(-cg));
    float rb = 1.0f/(1.0f + expf(-cb));

    // ---- masking ----
    const float sig_m = mask ? sigma : 0.0f;
    rr = mask ? rr : 0.0f;
    rg = mask ? rg : 0.0f;
    rb = mask ? rb : 0.0f;

    // ---- alpha, exclusive product scan (T_excl), weights ----
    const float alpha = 1.0f - expf(-fmaxf(sig_m, 0.0f) * STEP);
    float p = 1.0f - alpha + 1e-10f;

    float scan = p;
    #pragma unroll
    for (int off = 1; off < 64; off <<= 1) {
        const float n = __shfl_up(scan, off, 64);
        if (lane >= off) scan *= n;
    }
    if (lane == 63) s_wtot[wv] = scan;
    __syncthreads();

    float pre = 1.0f;
    #pragma unroll
    for (int q = 0; q < 4; ++q) if (q < wv) pre *= s_wtot[q];
    float excl = __shfl_up(scan, 1, 64);
    if (lane == 0) excl = 1.0f;
    const float Texcl = pre * excl;

    const float w = alpha * Texcl;
    float sw  = w;
    float swr = w * rr, swg = w * rg, swb = w * rb;

    // ---- block reduction ----
    #pragma unroll
    for (int off = 32; off > 0; off >>= 1) {
        sw  += __shfl_down(sw,  off, 64);
        swr += __shfl_down(swr, off, 64);
        swg += __shfl_down(swg, off, 64);
        swb += __shfl_down(swb, off, 64);
    }
    if (lane == 0) {
        s_red[wv][0] = sw;  s_red[wv][1] = swr;
        s_red[wv][2] = swg; s_red[wv][3] = swb;
    }
    __syncthreads();
    if (tid == 0) {
        float W = 0.0f, R = 0.0f, Gc = 0.0f, Bc = 0.0f;
        #pragma unroll
        for (int q = 0; q < 4; ++q) {
            W  += s_red[q][0]; R  += s_red[q][1];
            Gc += s_red[q][2]; Bc += s_red[q][3];
        }
        const float bg = 1.0f - W;
        out[b*3+0] = R  + bg;
        out[b*3+1] = Gc + bg;
        out[b*3+2] = Bc + bg;
    }
}

extern "C" void kernel_launch(void* const* d_in, const int* in_sizes, int n_in,
                              void* d_out, int out_size, void* d_ws, size_t ws_size,
                              hipStream_t stream) {
    const float* rays_o = (const float*)d_in[0];
    const float* rays_d = (const float*)d_in[1];
    const float* G1     = (const float*)d_in[2];
    const float* Fg     = (const float*)d_in[3];
    const float* Wd1    = (const float*)d_in[4];
    const float* bd1    = (const float*)d_in[5];
    const float* Wd2    = (const float*)d_in[6];
    const float* bd2    = (const float*)d_in[7];
    const float* Wc1    = (const float*)d_in[8];
    const float* bc1    = (const float*)d_in[9];
    const float* Wc2    = (const float*)d_in[10];
    const float* bc2    = (const float*)d_in[11];
    float* out = (float*)d_out;

    const int B = in_sizes[0] / 3;   // 2048 rays
    const size_t ft_bytes = (size_t)32768 * 32 * sizeof(float);

    if (ws_size >= ft_bytes) {
        float* Ft = (float*)d_ws;
        transpose_F<<<dim3(128), dim3(256), 0, stream>>>(Fg, Ft);
        nerf_fused<true><<<dim3(B), dim3(NSAMP), 0, stream>>>(
            rays_o, rays_d, G1, Fg, Wd1, bd1, Wd2, bd2, Wc1, bc1, Wc2, bc2, Ft, out);
    } else {
        nerf_fused<false><<<dim3(B), dim3(NSAMP), 0, stream>>>(
            rays_o, rays_d, G1, Fg, Wd1, bd1, Wd2, bd2, Wc1, bc1, Wc2, bc2, Fg, out);
    }
}

// Round 7
// 164.174 us; speedup vs baseline: 2.1815x; 1.3838x over previous
//
#include <hip/hip_runtime.h>
#include <hip/hip_fp16.h>
#include <math.h>

#define NSAMP 256

#if defined(__has_builtin)
#  if __has_builtin(__builtin_amdgcn_fdot2)
#    define HAVE_FDOT2 1
#  endif
#endif

typedef _Float16 h2 __attribute__((ext_vector_type(2)));

// ---------- pre-pass 1: transpose F [32ch][32768vox] -> Ft [vox][32ch] ----------
__global__ __launch_bounds__(256) void transpose_F(
    const float* __restrict__ Fg, float* __restrict__ Ft)
{
    const int j = blockIdx.x * 256 + threadIdx.x;   // voxel id 0..32767
    float4 o[8];
    #pragma unroll
    for (int q = 0; q < 8; ++q) {
        o[q].x = Fg[(size_t)(4*q+0)*32768 + j];
        o[q].y = Fg[(size_t)(4*q+1)*32768 + j];
        o[q].z = Fg[(size_t)(4*q+2)*32768 + j];
        o[q].w = Fg[(size_t)(4*q+3)*32768 + j];
    }
    float4* dst = (float4*)(Ft + (size_t)j * 32);
    #pragma unroll
    for (int q = 0; q < 8; ++q) dst[q] = o[q];
}

// ---------- pre-pass 2: pack layer-1 weights as half2 pairs over k ----------
// wdh[k2*64+j] = (Wd1[2k2][j], Wd1[2k2+1][j]);  same for Wc1 (first 32 rows).
__global__ __launch_bounds__(256) void pack_weights(
    const float* __restrict__ Wd1, const float* __restrict__ Wc1,
    __half2* __restrict__ wdh, __half2* __restrict__ wch)
{
    const int idx = blockIdx.x * 256 + threadIdx.x;  // 0..1023
    if (idx < 1024) {
        const int k2 = idx >> 6, j = idx & 63;
        wdh[idx] = __floats2half2_rn(Wd1[(2*k2)*64 + j], Wd1[(2*k2+1)*64 + j]);
        wch[idx] = __floats2half2_rn(Wc1[(2*k2)*64 + j], Wc1[(2*k2+1)*64 + j]);
    }
}

// ---------- main fused kernel ----------
template<bool USE_T>
__global__ __launch_bounds__(256) __attribute__((amdgpu_waves_per_eu(2, 4)))
void nerf_fused(
    const float* __restrict__ rays_o, const float* __restrict__ rays_d,
    const float* __restrict__ G1, const float* __restrict__ Fg,
    const float* __restrict__ Wd1, const float* __restrict__ bd1,
    const float* __restrict__ Wd2, const float* __restrict__ bd2,
    const float* __restrict__ Wc1, const float* __restrict__ bc1,
    const float* __restrict__ Wc2, const float* __restrict__ bc2,
    const float* __restrict__ Ft,
    const __half2* __restrict__ wdh, const __half2* __restrict__ wch,
    float* __restrict__ out)
{
    const float RADIUS = 1.3f;
    const float STEP = 0.0176f;

    const int b    = blockIdx.x;
    const int tid  = threadIdx.x;
    const int lane = tid & 63;
    const int wv   = tid >> 6;

    __shared__ float s_wtot[4];
    __shared__ float s_red[4][4];

    // ---- ray setup ----
    const float ox = rays_o[b*3+0], oy = rays_o[b*3+1], oz = rays_o[b*3+2];
    const float rdx = rays_d[b*3+0], rdy = rays_d[b*3+1], rdz = rays_d[b*3+2];
    const float rn  = sqrtf(rdx*rdx + rdy*rdy + rdz*rdz);
    const float dxn = rdx/rn, dyn = rdy/rn, dzn = rdz/rn;

    // ---- cube intersection ----
    float sd, inv, t1, t2, tmin, tmax;
    sd = (fabsf(dxn) < 1e-9f) ? 1e-9f : dxn; inv = 1.0f/sd;
    t1 = (-RADIUS - ox)*inv; t2 = (RADIUS - ox)*inv;
    tmin = fminf(t1,t2); tmax = fmaxf(t1,t2);
    sd = (fabsf(dyn) < 1e-9f) ? 1e-9f : dyn; inv = 1.0f/sd;
    t1 = (-RADIUS - oy)*inv; t2 = (RADIUS - oy)*inv;
    tmin = fmaxf(tmin, fminf(t1,t2)); tmax = fminf(tmax, fmaxf(t1,t2));
    sd = (fabsf(dzn) < 1e-9f) ? 1e-9f : dzn; inv = 1.0f/sd;
    t1 = (-RADIUS - oz)*inv; t2 = (RADIUS - oz)*inv;
    tmin = fmaxf(tmin, fminf(t1,t2)); tmax = fminf(tmax, fmaxf(t1,t2));

    const float tnear = fmaxf(tmin, 0.0f);
    const bool  hit   = tmax > tnear;
    const float t     = tnear + STEP * (float)tid;
    const bool  mask  = (t < tmax) && hit;

    float sigma = 0.0f, rr = 0.0f, rg = 0.0f, rb = 0.0f;

    // ---- wave-coherent early-out: masked samples are the ray tail, so
    //      whole waves are commonly all-masked -> skip gathers + MLP ----
    if (__any(mask)) {
        // ---- sample position, normalized to [-1,1] ----
        const float invR = 1.0f / RADIUS;
        const float px = (ox + t*dxn) * invR;
        const float py = (oy + t*dyn) * invR;
        const float pz = (oz + t*dzn) * invR;

        // ---- trilinear G1 (C=3, 128^3) ----
        float cox = fminf(fmaxf((px+1.0f)*0.5f*127.0f, 0.0f), 127.0f);
        float coy = fminf(fmaxf((py+1.0f)*0.5f*127.0f, 0.0f), 127.0f);
        float coz = fminf(fmaxf((pz+1.0f)*0.5f*127.0f, 0.0f), 127.0f);
        int x0 = (int)floorf(cox); float fx = cox - (float)x0; int x1 = min(x0+1, 127);
        int y0 = (int)floorf(coy); float fy = coy - (float)y0; int y1 = min(y0+1, 127);
        int z0 = (int)floorf(coz); float fz = coz - (float)z0; int z1 = min(z0+1, 127);

        {
            const float wx0 = 1.0f-fx, wx1 = fx;
            const float wy0 = 1.0f-fy, wy1 = fy;
            const float wz0 = 1.0f-fz, wz1 = fz;
            const float w000 = wx0*wy0*wz0, w100 = wx1*wy0*wz0;
            const float w010 = wx0*wy1*wz0, w110 = wx1*wy1*wz0;
            const float w001 = wx0*wy0*wz1, w101 = wx1*wy0*wz1;
            const float w011 = wx0*wy1*wz1, w111 = wx1*wy1*wz1;
            const int i000 = (z0*128 + y0)*128 + x0;
            const int dxo = x1 - x0;
            const int dyo = (y1 - y0)*128;
            const int dzo = (z1 - z0)*16384;
            const int i100 = i000 + dxo,       i010 = i000 + dyo;
            const int i110 = i000 + dyo + dxo, i001 = i000 + dzo;
            const int i101 = i000 + dzo + dxo, i011 = i000 + dzo + dyo;
            const int i111 = i000 + dzo + dyo + dxo;

            float g[3];
            #pragma unroll
            for (int c = 0; c < 3; ++c) {
                const float* gp = G1 + (size_t)c * 2097152;
                g[c] = w000*gp[i000] + w100*gp[i100] + w010*gp[i010] + w110*gp[i110]
                     + w001*gp[i001] + w101*gp[i101] + w011*gp[i011] + w111*gp[i111];
            }

            // ---- F coords from g ----
            cox = fminf(fmaxf((g[0]+1.0f)*0.5f*31.0f, 0.0f), 31.0f);
            coy = fminf(fmaxf((g[1]+1.0f)*0.5f*31.0f, 0.0f), 31.0f);
            coz = fminf(fmaxf((g[2]+1.0f)*0.5f*31.0f, 0.0f), 31.0f);
            x0 = (int)floorf(cox); fx = cox - (float)x0; x1 = min(x0+1, 31);
            y0 = (int)floorf(coy); fy = coy - (float)y0; y1 = min(y0+1, 31);
            z0 = (int)floorf(coz); fz = coz - (float)z0; z1 = min(z0+1, 31);
        }

        // ---- trilinear F (C=32), corner-at-a-time ----
        float feats[32];
        #pragma unroll
        for (int c = 0; c < 32; ++c) feats[c] = 0.0f;
        {
            const float wx0 = 1.0f-fx, wx1 = fx;
            const float wy0 = 1.0f-fy, wy1 = fy;
            const float wz0 = 1.0f-fz, wz1 = fz;
            const int j000 = (z0*32 + y0)*32 + x0;
            const int dxo = x1 - x0;
            const int dyo = (y1 - y0)*32;
            const int dzo = (z1 - z0)*1024;

            const int   jidx[8] = { j000,           j000+dxo,
                                    j000+dyo,       j000+dyo+dxo,
                                    j000+dzo,       j000+dzo+dxo,
                                    j000+dzo+dyo,   j000+dzo+dyo+dxo };
            const float jwt[8]  = { wx0*wy0*wz0, wx1*wy0*wz0,
                                    wx0*wy1*wz0, wx1*wy1*wz0,
                                    wx0*wy0*wz1, wx1*wy0*wz1,
                                    wx0*wy1*wz1, wx1*wy1*wz1 };

            if (USE_T) {
                #pragma unroll
                for (int corner = 0; corner < 8; ++corner) {
                    const float4* fp = (const float4*)(Ft + (size_t)jidx[corner] * 32);
                    const float w = jwt[corner];
                    #pragma unroll
                    for (int q = 0; q < 8; ++q) {
                        const float4 v = fp[q];
                        feats[4*q+0] += w * v.x;
                        feats[4*q+1] += w * v.y;
                        feats[4*q+2] += w * v.z;
                        feats[4*q+3] += w * v.w;
                    }
                }
            } else {
                #pragma unroll
                for (int corner = 0; corner < 8; ++corner) {
                    const float w = jwt[corner];
                    const int  j  = jidx[corner];
                    #pragma unroll
                    for (int c = 0; c < 32; ++c)
                        feats[c] += w * Fg[(size_t)c * 32768 + j];
                }
            }
        }

        // ---- fused MLPs ----
        sigma = bd2[0];
        float cr = 0.0f, cg = 0.0f, cb = 0.0f;

#ifdef HAVE_FDOT2
        // pack feats into half2 pairs (fp32 accumulate in dot2 -> safe at 2e-2 tol)
        h2 fh[16];
        #pragma unroll
        for (int i = 0; i < 16; ++i) {
            __half2 ph = __floats2half2_rn(feats[2*i], feats[2*i+1]);
            fh[i] = *reinterpret_cast<h2*>(&ph);
        }
        for (int j0 = 0; j0 < 64; j0 += 8) {
            float ad[8], ac[8];
            #pragma unroll
            for (int jj = 0; jj < 8; ++jj) {
                ad[jj] = bd1[j0+jj];
                ac[jj] = bc1[j0+jj] + dxn*Wc1[32*64 + j0 + jj]
                                    + dyn*Wc1[33*64 + j0 + jj]
                                    + dzn*Wc1[34*64 + j0 + jj];
            }
            #pragma unroll
            for (int k2 = 0; k2 < 16; ++k2) {
                const h2 fv = fh[k2];
                #pragma unroll
                for (int jj = 0; jj < 8; ++jj) {
                    __half2 wd = wdh[k2*64 + j0 + jj];
                    __half2 wc = wch[k2*64 + j0 + jj];
                    ad[jj] = __builtin_amdgcn_fdot2(fv, *reinterpret_cast<h2*>(&wd), ad[jj], false);
                    ac[jj] = __builtin_amdgcn_fdot2(fv, *reinterpret_cast<h2*>(&wc), ac[jj], false);
                }
            }
            #pragma unroll
            for (int jj = 0; jj < 8; ++jj) {
                sigma += fmaxf(ad[jj], 0.0f) * Wd2[j0+jj];
                const float hc = fmaxf(ac[jj], 0.0f);
                cr += hc * Wc2[(j0+jj)*3 + 0];
                cg += hc * Wc2[(j0+jj)*3 + 1];
                cb += hc * Wc2[(j0+jj)*3 + 2];
            }
        }
#else
        for (int j0 = 0; j0 < 64; j0 += 8) {
            float ad[8], ac[8];
            #pragma unroll
            for (int jj = 0; jj < 8; ++jj) {
                ad[jj] = bd1[j0+jj];
                ac[jj] = bc1[j0+jj] + dxn*Wc1[32*64 + j0 + jj]
                                    + dyn*Wc1[33*64 + j0 + jj]
                                    + dzn*Wc1[34*64 + j0 + jj];
            }
            #pragma unroll
            for (int k = 0; k < 32; ++k) {
                const float fv = feats[k];
                #pragma unroll
                for (int jj = 0; jj < 8; ++jj) {
                    ad[jj] += fv * Wd1[k*64 + j0 + jj];
                    ac[jj] += fv * Wc1[k*64 + j0 + jj];
                }
            }
            #pragma unroll
            for (int jj = 0; jj < 8; ++jj) {
                sigma += fmaxf(ad[jj], 0.0f) * Wd2[j0+jj];
                const float hc = fmaxf(ac[jj], 0.0f);
                cr += hc * Wc2[(j0+jj)*3 + 0];
                cg += hc * Wc2[(j0+jj)*3 + 1];
                cb += hc * Wc2[(j0+jj)*3 + 2];
            }
        }
#endif
        cr += bc2[0]; cg += bc2[1]; cb += bc2[2];
        rr = 1.0f/(1.0f + expf(-cr));
        rg = 1.0f/(1.0f + expf(-cg));
        rb = 1.0f/(1.0f + expf(-cb));

        // per-lane masking
        sigma = mask ? sigma : 0.0f;
        rr = mask ? rr : 0.0f;
        rg = mask ? rg : 0.0f;
        rb = mask ? rb : 0.0f;
    }

    // ---- alpha, exclusive product scan (T_excl), weights ----
    const float alpha = 1.0f - expf(-fmaxf(sigma, 0.0f) * STEP);
    float p = 1.0f - alpha + 1e-10f;

    float scan = p;
    #pragma unroll
    for (int off = 1; off < 64; off <<= 1) {
        const float n = __shfl_up(scan, off, 64);
        if (lane >= off) scan *= n;
    }
    if (lane == 63) s_wtot[wv] = scan;
    __syncthreads();

    float pre = 1.0f;
    #pragma unroll
    for (int q = 0; q < 4; ++q) if (q < wv) pre *= s_wtot[q];
    float excl = __shfl_up(scan, 1, 64);
    if (lane == 0) excl = 1.0f;
    const float Texcl = pre * excl;

    const float w = alpha * Texcl;
    float sw  = w;
    float swr = w * rr, swg = w * rg, swb = w * rb;

    // ---- block reduction ----
    #pragma unroll
    for (int off = 32; off > 0; off >>= 1) {
        sw  += __shfl_down(sw,  off, 64);
        swr += __shfl_down(swr, off, 64);
        swg += __shfl_down(swg, off, 64);
        swb += __shfl_down(swb, off, 64);
    }
    if (lane == 0) {
        s_red[wv][0] = sw;  s_red[wv][1] = swr;
        s_red[wv][2] = swg; s_red[wv][3] = swb;
    }
    __syncthreads();
    if (tid == 0) {
        float W = 0.0f, R = 0.0f, Gc = 0.0f, Bc = 0.0f;
        #pragma unroll
        for (int q = 0; q < 4; ++q) {
            W  += s_red[q][0]; R  += s_red[q][1];
            Gc += s_red[q][2]; Bc += s_red[q][3];
        }
        const float bg = 1.0f - W;
        out[b*3+0] = R  + bg;
        out[b*3+1] = Gc + bg;
        out[b*3+2] = Bc + bg;
    }
}

extern "C" void kernel_launch(void* const* d_in, const int* in_sizes, int n_in,
                              void* d_out, int out_size, void* d_ws, size_t ws_size,
                              hipStream_t stream) {
    const float* rays_o = (const float*)d_in[0];
    const float* rays_d = (const float*)d_in[1];
    const float* G1     = (const float*)d_in[2];
    const float* Fg     = (const float*)d_in[3];
    const float* Wd1    = (const float*)d_in[4];
    const float* bd1    = (const float*)d_in[5];
    const float* Wd2    = (const float*)d_in[6];
    const float* bd2    = (const float*)d_in[7];
    const float* Wc1    = (const float*)d_in[8];
    const float* bc1    = (const float*)d_in[9];
    const float* Wc2    = (const float*)d_in[10];
    const float* bc2    = (const float*)d_in[11];
    float* out = (float*)d_out;

    const int B = in_sizes[0] / 3;   // 2048 rays
    const size_t ft_bytes = (size_t)32768 * 32 * sizeof(float);   // 4 MB
    const size_t pk_bytes = (size_t)1024 * sizeof(__half2);       // 4 KB each

    if (ws_size >= ft_bytes + 2*pk_bytes) {
        float*   Ft  = (float*)d_ws;
        __half2* wdh = (__half2*)((char*)d_ws + ft_bytes);
        __half2* wch = (__half2*)((char*)d_ws + ft_bytes + pk_bytes);
        transpose_F<<<dim3(128), dim3(256), 0, stream>>>(Fg, Ft);
        pack_weights<<<dim3(4), dim3(256), 0, stream>>>(Wd1, Wc1, wdh, wch);
        nerf_fused<true><<<dim3(B), dim3(NSAMP), 0, stream>>>(
            rays_o, rays_d, G1, Fg, Wd1, bd1, Wd2, bd2, Wc1, bc1, Wc2, bc2,
            Ft, wdh, wch, out);
    } else {
        __half2* wdh = (__half2*)d_ws;
        __half2* wch = wdh + 1024;
        if (ws_size >= 2*pk_bytes)
            pack_weights<<<dim3(4), dim3(256), 0, stream>>>(Wd1, Wc1, wdh, wch);
        nerf_fused<false><<<dim3(B), dim3(NSAMP), 0, stream>>>(
            rays_o, rays_d, G1, Fg, Wd1, bd1, Wd2, bd2, Wc1, bc1, Wc2, bc2,
            Fg, wdh, wch, out);
    }
}